// Round 2
// baseline (361.036 us; speedup 1.0000x reference)
//
#include <hip/hip_runtime.h>

#define D_FEAT 32

// ---------- shared small kernels ----------

__global__ void norm_kernel(const int* __restrict__ deg, float* __restrict__ norm, int n_nodes) {
    int i = blockIdx.x * blockDim.x + threadIdx.x;
    if (i < n_nodes) {
        int d = deg[i];
        norm[i] = d > 0 ? rsqrtf((float)d) : 0.0f;
    }
}

// ---------- CSR path ----------

// Both histograms in one pass: out-degree over src (for norm), in-degree over dst (for CSR).
__global__ void hist_kernel(const int* __restrict__ src, const int* __restrict__ dst,
                            int* __restrict__ deg_out, int* __restrict__ deg_in, int n_edges) {
    int e = blockIdx.x * blockDim.x + threadIdx.x;
    if (e < n_edges) {
        atomicAdd(&deg_out[src[e]], 1);
        atomicAdd(&deg_in[dst[e]], 1);
    }
}

// Per-node chunk start offsets. Chunk placement order is irrelevant (each node just
// needs a private contiguous region), so: wave-level inclusive scan + ONE atomic per wave.
__global__ void offsets_kernel(const int* __restrict__ deg_in, int* __restrict__ start,
                               int* __restrict__ total, int n_nodes) {
    int i = blockIdx.x * blockDim.x + threadIdx.x;
    int lane = threadIdx.x & 63;
    int v = (i < n_nodes) ? deg_in[i] : 0;
    int scan = v;
    #pragma unroll
    for (int off = 1; off < 64; off <<= 1) {
        int t = __shfl_up(scan, off);
        if (lane >= off) scan += t;
    }
    int wtot = __shfl(scan, 63);
    int base = 0;
    if (lane == 63) base = atomicAdd(total, wtot);
    base = __shfl(base, 63);
    if (i < n_nodes) start[i] = base + scan - v;
}

// Bucket each edge's src-id into its dst node's chunk. 4 B payload, int atomics only.
__global__ void edge_scatter_kernel(const int* __restrict__ src, const int* __restrict__ dst,
                                    const int* __restrict__ start, int* __restrict__ cursor,
                                    int* __restrict__ sorted_src, int n_edges) {
    int e = blockIdx.x * blockDim.x + threadIdx.x;
    if (e < n_edges) {
        int d = dst[e];
        int pos = start[d] + atomicAdd(&cursor[d], 1);
        sorted_src[pos] = src[e];
    }
}

// Pull-gather: 32 lanes per dst node, lane = feature dim. Batch-load 32 edges'
// src-ids + norms, shfl-broadcast, accumulate in registers, one coalesced write.
__global__ void gather_kernel(const float* __restrict__ feat,
                              const int* __restrict__ sorted_src,
                              const int* __restrict__ start,
                              const int* __restrict__ deg_in,
                              const float* __restrict__ norm,
                              float* __restrict__ out, int n_nodes) {
    int t = blockIdx.x * blockDim.x + threadIdx.x;
    int i = t >> 5;        // dst node
    int lane = t & 31;     // feature dim
    if (i >= n_nodes) return;

    int s0 = start[i];
    int dg = deg_in[i];
    float acc = 0.0f;

    int k = 0;
    while (k < dg) {
        int batch = dg - k;
        if (batch > 32) batch = 32;
        int sid = 0;
        float nv = 0.0f;
        if (lane < batch) {
            sid = sorted_src[s0 + k + lane];
            nv = norm[sid];
        }
        for (int j = 0; j < batch; ++j) {
            int s   = __shfl(sid, j, 32);
            float w = __shfl(nv, j, 32);
            acc += feat[s * D_FEAT + lane] * w;
        }
        k += batch;
    }
    out[i * D_FEAT + lane] = acc * norm[i];
}

// ---------- fallback (R1 atomic path) ----------

__global__ void deg_kernel(const int* __restrict__ src, int* __restrict__ deg, int n_edges) {
    int e = blockIdx.x * blockDim.x + threadIdx.x;
    if (e < n_edges) atomicAdd(&deg[src[e]], 1);
}

__global__ void scatter_kernel(const float* __restrict__ feat,
                               const int* __restrict__ src,
                               const int* __restrict__ dst,
                               const float* __restrict__ norm,
                               float* __restrict__ out, int n_edges) {
    int t = blockIdx.x * blockDim.x + threadIdx.x;
    int e = t >> 5;
    int d = t & 31;
    if (e < n_edges) {
        int s  = src[e];
        int dd = dst[e];
        float v = feat[s * D_FEAT + d] * norm[s];
        atomicAdd(&out[dd * D_FEAT + d], v);
    }
}

__global__ void post_scale_kernel(float4* __restrict__ out4,
                                  const float* __restrict__ norm, int n4) {
    int t = blockIdx.x * blockDim.x + threadIdx.x;
    if (t < n4) {
        float nv = norm[t >> 3];
        float4 v = out4[t];
        v.x *= nv; v.y *= nv; v.z *= nv; v.w *= nv;
        out4[t] = v;
    }
}

// ---------- launch ----------

extern "C" void kernel_launch(void* const* d_in, const int* in_sizes, int n_in,
                              void* d_out, int out_size, void* d_ws, size_t ws_size,
                              hipStream_t stream) {
    const float* feat = (const float*)d_in[0];
    const int*   src  = (const int*)d_in[1];
    const int*   dst  = (const int*)d_in[2];
    float* out = (float*)d_out;

    const int n_nodes = in_sizes[0] / D_FEAT;
    const int n_edges = in_sizes[1];
    const int B = 256;

    size_t nN = (size_t)n_nodes * sizeof(int);
    size_t nNa = (nN + 255) & ~(size_t)255;  // 256-aligned per-node array stride
    size_t nE = (size_t)n_edges * sizeof(int);

    // layout: [deg_out][deg_in][cursor][total(256B)] | [start][norm][sorted_src]
    size_t need = nNa * 5 + 256 + nE;

    if (ws_size >= need) {
        char* w = (char*)d_ws;
        int*   deg_out    = (int*)(w);
        int*   deg_in     = (int*)(w + nNa);
        int*   cursor     = (int*)(w + 2 * nNa);
        int*   total      = (int*)(w + 3 * nNa);
        int*   start      = (int*)(w + 3 * nNa + 256);
        float* norm       = (float*)(w + 4 * nNa + 256);
        int*   sorted_src = (int*)(w + 5 * nNa + 256);

        // single memset covers deg_out, deg_in, cursor, total
        hipMemsetAsync(w, 0, 3 * nNa + 256, stream);

        hist_kernel<<<(n_edges + B - 1) / B, B, 0, stream>>>(src, dst, deg_out, deg_in, n_edges);
        norm_kernel<<<(n_nodes + B - 1) / B, B, 0, stream>>>(deg_out, norm, n_nodes);
        offsets_kernel<<<(n_nodes + B - 1) / B, B, 0, stream>>>(deg_in, start, total, n_nodes);
        edge_scatter_kernel<<<(n_edges + B - 1) / B, B, 0, stream>>>(src, dst, start, cursor,
                                                                     sorted_src, n_edges);
        long long gt = (long long)n_nodes * 32;
        gather_kernel<<<(int)((gt + B - 1) / B), B, 0, stream>>>(feat, sorted_src, start,
                                                                 deg_in, norm, out, n_nodes);
    } else {
        // fallback: R1 atomic-scatter path (needs only 2 per-node arrays)
        int*   deg  = (int*)d_ws;
        float* norm = (float*)((char*)d_ws + nNa);

        hipMemsetAsync(deg, 0, nN, stream);
        hipMemsetAsync(d_out, 0, (size_t)out_size * sizeof(float), stream);

        deg_kernel<<<(n_edges + B - 1) / B, B, 0, stream>>>(src, deg, n_edges);
        norm_kernel<<<(n_nodes + B - 1) / B, B, 0, stream>>>(deg, norm, n_nodes);

        long long total = (long long)n_edges * 32;
        scatter_kernel<<<(int)((total + B - 1) / B), B, 0, stream>>>(feat, src, dst, norm, out, n_edges);

        int n4 = out_size / 4;
        post_scale_kernel<<<(n4 + B - 1) / B, B, 0, stream>>>((float4*)out, norm, n4);
    }
}

// Round 3
// 330.831 us; speedup vs baseline: 1.0913x; 1.0913x over previous
//
#include <hip/hip_runtime.h>

#define D_FEAT 32
#define N_XCD 8

// Physical accelerator-complex-die id (0..7 on MI355X). Wave-uniform; all waves
// of a workgroup run on one CU -> one XCD, so shard choice is consistent.
__device__ __forceinline__ int get_xcc() {
    int x;
    asm volatile("s_getreg_b32 %0, hwreg(HW_REG_XCC_ID, 0, 4)" : "=s"(x));
    return x & (N_XCD - 1);
}

// L2-local (workgroup-scope) atomic add: executes in the issuing XCD's TCC,
// cached, no memory-side round trip. Safe ONLY on XCD-private data.
__device__ __forceinline__ void atom_add_local(float* p, float v) {
    __hip_atomic_fetch_add(p, v, __ATOMIC_RELAXED, __HIP_MEMORY_SCOPE_WORKGROUP);
}
__device__ __forceinline__ void atom_add_local(int* p, int v) {
    __hip_atomic_fetch_add(p, v, __ATOMIC_RELAXED, __HIP_MEMORY_SCOPE_WORKGROUP);
}

// ---------- sharded path ----------

__global__ void hist_shard_kernel(const int* __restrict__ src, int* __restrict__ deg_shards,
                                  size_t shard_stride, int n_edges) {
    int e = blockIdx.x * blockDim.x + threadIdx.x;
    if (e < n_edges) {
        int* shard = deg_shards + (size_t)get_xcc() * shard_stride;
        atom_add_local(&shard[src[e]], 1);
    }
}

__global__ void norm_from_shards_kernel(const int* __restrict__ deg_shards, size_t shard_stride,
                                        float* __restrict__ norm, int n_nodes) {
    int i = blockIdx.x * blockDim.x + threadIdx.x;
    if (i < n_nodes) {
        int d = 0;
        #pragma unroll
        for (int s = 0; s < N_XCD; ++s) d += deg_shards[(size_t)s * shard_stride + i];
        norm[i] = d > 0 ? rsqrtf((float)d) : 0.0f;
    }
}

// 32 lanes per edge (lane = feature dim); atomics into the local XCD's shard.
__global__ void scatter_shard_kernel(const float* __restrict__ feat,
                                     const int* __restrict__ src,
                                     const int* __restrict__ dst,
                                     const float* __restrict__ norm,
                                     float* __restrict__ out_shards,
                                     size_t shard_elems, int n_edges) {
    int t = blockIdx.x * blockDim.x + threadIdx.x;
    int e = t >> 5;
    int d = t & 31;
    if (e >= n_edges) return;
    float* shard = out_shards + (size_t)get_xcc() * shard_elems;
    int s  = src[e];
    int dd = dst[e];
    float v = feat[(size_t)s * D_FEAT + d] * norm[s];
    atom_add_local(&shard[(size_t)dd * D_FEAT + d], v);
}

// out = (sum of 8 shards) * norm[node]; one thread per float4.
__global__ void combine_kernel(const float4* __restrict__ shards4, size_t shard_elems4,
                               const float* __restrict__ norm,
                               float4* __restrict__ out4, int n4) {
    int t = blockIdx.x * blockDim.x + threadIdx.x;
    if (t >= n4) return;
    float4 a = shards4[t];
    #pragma unroll
    for (int s = 1; s < N_XCD; ++s) {
        float4 b = shards4[(size_t)s * shard_elems4 + t];
        a.x += b.x; a.y += b.y; a.z += b.z; a.w += b.w;
    }
    float nv = norm[t >> 3];  // 8 float4 per node row
    a.x *= nv; a.y *= nv; a.z *= nv; a.w *= nv;
    out4[t] = a;
}

// ---------- fallback (device-scope atomics, R1 structure) ----------

__global__ void deg_kernel(const int* __restrict__ src, int* __restrict__ deg, int n_edges) {
    int e = blockIdx.x * blockDim.x + threadIdx.x;
    if (e < n_edges) atomicAdd(&deg[src[e]], 1);
}

__global__ void norm_kernel(const int* __restrict__ deg, float* __restrict__ norm, int n_nodes) {
    int i = blockIdx.x * blockDim.x + threadIdx.x;
    if (i < n_nodes) {
        int d = deg[i];
        norm[i] = d > 0 ? rsqrtf((float)d) : 0.0f;
    }
}

__global__ void scatter_kernel(const float* __restrict__ feat,
                               const int* __restrict__ src,
                               const int* __restrict__ dst,
                               const float* __restrict__ norm,
                               float* __restrict__ out, int n_edges) {
    int t = blockIdx.x * blockDim.x + threadIdx.x;
    int e = t >> 5;
    int d = t & 31;
    if (e < n_edges) {
        int s  = src[e];
        int dd = dst[e];
        float v = feat[(size_t)s * D_FEAT + d] * norm[s];
        atomicAdd(&out[(size_t)dd * D_FEAT + d], v);
    }
}

__global__ void post_scale_kernel(float4* __restrict__ out4,
                                  const float* __restrict__ norm, int n4) {
    int t = blockIdx.x * blockDim.x + threadIdx.x;
    if (t < n4) {
        float nv = norm[t >> 3];
        float4 v = out4[t];
        v.x *= nv; v.y *= nv; v.z *= nv; v.w *= nv;
        out4[t] = v;
    }
}

// ---------- launch ----------

extern "C" void kernel_launch(void* const* d_in, const int* in_sizes, int n_in,
                              void* d_out, int out_size, void* d_ws, size_t ws_size,
                              hipStream_t stream) {
    const float* feat = (const float*)d_in[0];
    const int*   src  = (const int*)d_in[1];
    const int*   dst  = (const int*)d_in[2];
    float* out = (float*)d_out;

    const int n_nodes = in_sizes[0] / D_FEAT;
    const int n_edges = in_sizes[1];
    const int B = 256;

    size_t nNa  = (((size_t)n_nodes * sizeof(int)) + 255) & ~(size_t)255;
    size_t outB = (((size_t)out_size * sizeof(float)) + 255) & ~(size_t)255;

    // sharded layout: [deg_shards 8*nNa][out_shards 8*outB][norm nNa]
    size_t need_full = (size_t)N_XCD * nNa + (size_t)N_XCD * outB + nNa;

    if (ws_size >= need_full) {
        char* w = (char*)d_ws;
        int*   deg_shards = (int*)w;
        float* out_shards = (float*)(w + (size_t)N_XCD * nNa);
        float* norm       = (float*)(w + (size_t)N_XCD * nNa + (size_t)N_XCD * outB);

        // one contiguous zero over deg_shards + out_shards
        hipMemsetAsync(w, 0, (size_t)N_XCD * nNa + (size_t)N_XCD * outB, stream);

        size_t deg_stride = nNa / sizeof(int);
        size_t shard_elems = outB / sizeof(float);

        hist_shard_kernel<<<(n_edges + B - 1) / B, B, 0, stream>>>(src, deg_shards, deg_stride, n_edges);
        norm_from_shards_kernel<<<(n_nodes + B - 1) / B, B, 0, stream>>>(deg_shards, deg_stride, norm, n_nodes);

        long long st = (long long)n_edges * 32;
        scatter_shard_kernel<<<(int)((st + B - 1) / B), B, 0, stream>>>(feat, src, dst, norm,
                                                                        out_shards, shard_elems, n_edges);

        int n4 = out_size / 4;
        combine_kernel<<<(n4 + B - 1) / B, B, 0, stream>>>((const float4*)out_shards, shard_elems / 4,
                                                           norm, (float4*)out, n4);
    } else if (ws_size >= (size_t)(N_XCD + 2) * nNa) {
        // sharded degree histogram + device-scope scatter
        char* w = (char*)d_ws;
        int*   deg_shards = (int*)w;
        float* norm       = (float*)(w + (size_t)N_XCD * nNa);

        hipMemsetAsync(w, 0, (size_t)N_XCD * nNa, stream);
        hipMemsetAsync(d_out, 0, (size_t)out_size * sizeof(float), stream);

        size_t deg_stride = nNa / sizeof(int);
        hist_shard_kernel<<<(n_edges + B - 1) / B, B, 0, stream>>>(src, deg_shards, deg_stride, n_edges);
        norm_from_shards_kernel<<<(n_nodes + B - 1) / B, B, 0, stream>>>(deg_shards, deg_stride, norm, n_nodes);

        long long st = (long long)n_edges * 32;
        scatter_kernel<<<(int)((st + B - 1) / B), B, 0, stream>>>(feat, src, dst, norm, out, n_edges);
        int n4 = out_size / 4;
        post_scale_kernel<<<(n4 + B - 1) / B, B, 0, stream>>>((float4*)out, norm, n4);
    } else {
        // minimal fallback
        int*   deg  = (int*)d_ws;
        float* norm = (float*)((char*)d_ws + nNa);

        hipMemsetAsync(deg, 0, (size_t)n_nodes * sizeof(int), stream);
        hipMemsetAsync(d_out, 0, (size_t)out_size * sizeof(float), stream);

        deg_kernel<<<(n_edges + B - 1) / B, B, 0, stream>>>(src, deg, n_edges);
        norm_kernel<<<(n_nodes + B - 1) / B, B, 0, stream>>>(deg, norm, n_nodes);

        long long st = (long long)n_edges * 32;
        scatter_kernel<<<(int)((st + B - 1) / B), B, 0, stream>>>(feat, src, dst, norm, out, n_edges);
        int n4 = out_size / 4;
        post_scale_kernel<<<(n4 + B - 1) / B, B, 0, stream>>>((float4*)out, norm, n4);
    }
}